// Round 8
// baseline (511.683 us; speedup 1.0000x reference)
//
#include <hip/hip_runtime.h>
#include <hip/hip_bf16.h>

#define NN 50000
#define NE 800000
#define DD 512
#define NPAD 50048   // 391 * 128, for 128-row GEMM tiles
#define STRIDE 96    // bucket-CSR slot count; P(deg >= 96) ~ 1e-30 for Poisson(16)

typedef __attribute__((ext_vector_type(8))) short bf16x8;
typedef __attribute__((ext_vector_type(4))) float f32x4;
typedef __attribute__((ext_vector_type(8))) unsigned short u16x8;

// R8 = R6 EXACTLY + TWO duplicate gemm launches (idempotent) as an attribution
// probe: gemm_dur ~= (total - 403.2)/2. R7 (same probe, x1) died to an infra
// failure before running. prep/gemm have never been directly visible (below
// the ~131 us top-5 cut); three structural bets on the 272 us non-aggregate
// residue moved <= 5 us, so the component model is wrong somewhere. Buy data.
__device__ __align__(16) unsigned short g_Wt[DD * DD];            // W^T bf16
__device__ __align__(16) unsigned short g_xb[(size_t)NN * DD];    // x in bf16 (51 MB)
__device__ __align__(16) unsigned short g_agg[(size_t)NPAD * DD]; // bf16 agg (A matrix)
__device__ unsigned g_cnt[NN];                                    // static zero-init
__device__ int g_eidx[(size_t)NN * STRIDE];                       // bucket CSR

// round-to-nearest-even fp32 -> bf16 (finite normal inputs)
static __device__ __forceinline__ unsigned short f2bf(float f) {
    unsigned u = __float_as_uint(f);
    u += 0x7fff + ((u >> 16) & 1);
    return (unsigned short)(u >> 16);
}
static __device__ __forceinline__ float bf2f(unsigned short u) {
    return __uint_as_float((unsigned)u << 16);
}

// Fused prep: fill (edge scatter) runs CONCURRENTLY with x->bf16 conv, W^T, pad-zero.
#define FB_FILL 3125                 // 800000 / 256 exactly
#define FB_CONV (FB_FILL + 12500)    // 50000*512/8/256
#define FB_WT   (FB_CONV + 1024)     // 512*512/256
#define FB_END  (FB_WT + 12)         // 48 pad rows * 512 / 8 / 256

__global__ void prep_all(const float* __restrict__ x, const float* __restrict__ W,
                         const int* __restrict__ src, const int* __restrict__ dst) {
    int b = blockIdx.x;
    int tid = threadIdx.x;
    if (b < FB_FILL) {
        int i = b * 256 + tid;                     // NE = 3125*256 exactly
        int d = dst[i];
        unsigned pos = atomicAdd(&g_cnt[d], 1u);
        if (pos < STRIDE) g_eidx[(size_t)d * STRIDE + pos] = src[i];
    } else if (b < FB_CONV) {
        size_t base = ((size_t)(b - FB_FILL) * 256 + tid) * 8;
        // x is read exactly once: nontemporal load, don't install 102 MB in L2
        f32x4 v0 = __builtin_nontemporal_load((const f32x4*)(x + base));
        f32x4 v1 = __builtin_nontemporal_load((const f32x4*)(x + base) + 1);
        u16x8 o;
        o[0] = f2bf(v0[0]); o[1] = f2bf(v0[1]); o[2] = f2bf(v0[2]); o[3] = f2bf(v0[3]);
        o[4] = f2bf(v1[0]); o[5] = f2bf(v1[1]); o[6] = f2bf(v1[2]); o[7] = f2bf(v1[3]);
        *(u16x8*)(g_xb + base) = o;                // normal store
    } else if (b < FB_WT) {
        int idx = (b - FB_CONV) * 256 + tid;       // coalesced read of W
        int k = idx >> 9, n = idx & 511;
        g_Wt[n * DD + k] = f2bf(W[idx]);           // g_Wt[n][k] = W[k][n]
    } else {
        int i = (b - FB_WT) * 256 + tid;           // 0..3071: zero 48 GEMM pad rows
        u16x8 z = {0, 0, 0, 0, 0, 0, 0, 0};
        *(u16x8*)(g_agg + (size_t)NN * DD + (size_t)i * 8) = z;
    }
}

// one wave per node: gather bf16 rows, fp32 register accumulation, bf16 write.
// Structurally done: 418 MB random-line fetch @ ~3.3 TB/s fabric wall (R3 MLP
// A/B flat; R5 slicing regressed badly).
__global__ void aggregate() {
    int v = (blockIdx.x * blockDim.x + threadIdx.x) >> 6;
    int lane = threadIdx.x & 63;
    if (v >= NN) return;
    int deg = (int)g_cnt[v];
    if (deg > STRIDE) deg = STRIDE;
    const int* seg = g_eidx + (size_t)v * STRIDE;
    float a[8] = {0.f, 0.f, 0.f, 0.f, 0.f, 0.f, 0.f, 0.f};
    int i = 0;
    for (; i + 3 < deg; i += 4) {  // 4 KB in flight per wave
        int s0 = seg[i], s1 = seg[i + 1], s2 = seg[i + 2], s3 = seg[i + 3];
        int4 q0 = *((const int4*)(g_xb + ((size_t)s0 << 9)) + lane);
        int4 q1 = *((const int4*)(g_xb + ((size_t)s1 << 9)) + lane);
        int4 q2 = *((const int4*)(g_xb + ((size_t)s2 << 9)) + lane);
        int4 q3 = *((const int4*)(g_xb + ((size_t)s3 << 9)) + lane);
        const unsigned short* u0 = (const unsigned short*)&q0;
        const unsigned short* u1 = (const unsigned short*)&q1;
        const unsigned short* u2 = (const unsigned short*)&q2;
        const unsigned short* u3 = (const unsigned short*)&q3;
#pragma unroll
        for (int j = 0; j < 8; ++j)
            a[j] += (bf2f(u0[j]) + bf2f(u1[j])) + (bf2f(u2[j]) + bf2f(u3[j]));
    }
    for (; i + 1 < deg; i += 2) {
        int s0 = seg[i], s1 = seg[i + 1];
        int4 q0 = *((const int4*)(g_xb + ((size_t)s0 << 9)) + lane);
        int4 q1 = *((const int4*)(g_xb + ((size_t)s1 << 9)) + lane);
        const unsigned short* u0 = (const unsigned short*)&q0;
        const unsigned short* u1 = (const unsigned short*)&q1;
#pragma unroll
        for (int j = 0; j < 8; ++j) a[j] += bf2f(u0[j]) + bf2f(u1[j]);
    }
    if (i < deg) {
        int s0 = seg[i];
        int4 q0 = *((const int4*)(g_xb + ((size_t)s0 << 9)) + lane);
        const unsigned short* u0 = (const unsigned short*)&q0;
#pragma unroll
        for (int j = 0; j < 8; ++j) a[j] += bf2f(u0[j]);
    }
    u16x8 o;
#pragma unroll
    for (int j = 0; j < 8; ++j) o[j] = f2bf(a[j]);
    *(u16x8*)(g_agg + ((size_t)v << 9) + lane * 8) = o;
}

// GEMM: m97 fragment structure, 128x256 tile, BK=32, 8 waves (2x4), 4x4 frags/wave.
// Idempotent (same inputs -> same out; g_cnt zeroed to 0 repeatedly is safe),
// so it can be launched multiple times for attribution.
#define BM 128
#define BN 256
#define BK 32
#define NWG ((NPAD / BM) * (DD / BN))   // 391*2 = 782

__global__ __launch_bounds__(512) void gemm_kernel(float* __restrict__ out,
                                                   const float* __restrict__ bias) {
    __shared__ __align__(16) unsigned short As[BM * BK];   // 8 KB, [m][k] linear
    __shared__ __align__(16) unsigned short Bs[BN * BK];   // 16 KB, [n][k] linear

    // zero g_cnt for the NEXT graph replay (runs after aggregate's last read).
    {
        int gid = blockIdx.x * 512 + threadIdx.x;   // 782*512 >= NN
        if (gid < NN) g_cnt[gid] = 0;
    }

    // bijective XCD swizzle (m204 form; NWG = 782, r = 6)
    const int q = NWG >> 3, r = NWG & 7;
    int xcd = blockIdx.x & 7, sub = blockIdx.x >> 3;
    int swz = (xcd < r) ? xcd * (q + 1) + sub : r * (q + 1) + (xcd - r) * q + sub;
    const int m0 = (swz >> 1) * BM;
    const int n0 = (swz & 1) * BN;

    const int tid = threadIdx.x;
    const int wave = tid >> 6, lane = tid & 63;
    const int wm = wave >> 2, wn = wave & 3;       // 2x4 waves -> 64x64 quadrants
    const int quad = lane >> 4, l16 = lane & 15;

    const int srow = lane >> 2;          // staging: 0..15
    const int skoff = (lane & 3) * 8;    // shorts

    f32x4 acc[4][4];
#pragma unroll
    for (int i = 0; i < 4; ++i)
#pragma unroll
        for (int j = 0; j < 4; ++j) acc[i][j] = (f32x4){0.f, 0.f, 0.f, 0.f};

    const unsigned short* gA = g_agg + (size_t)m0 * DD;
    const unsigned short* gB = g_Wt + (size_t)n0 * DD;

    for (int k0 = 0; k0 < DD; k0 += BK) {
        // 24 chunks of 1 KB (A: 0..7, B: 8..23), 3 per wave; wave-uniform LDS
        // base, HW adds lane*16 -> linear [row][k].
#pragma unroll
        for (int i = 0; i < 3; ++i) {
            int c = wave * 3 + i;
            if (c < 8) {
                __builtin_amdgcn_global_load_lds(
                    (const __attribute__((address_space(1))) void*)
                        (gA + (size_t)(c * 16 + srow) * DD + k0 + skoff),
                    (__attribute__((address_space(3))) void*)(As + c * 512), 16, 0, 0);
            } else {
                __builtin_amdgcn_global_load_lds(
                    (const __attribute__((address_space(1))) void*)
                        (gB + (size_t)((c - 8) * 16 + srow) * DD + k0 + skoff),
                    (__attribute__((address_space(3))) void*)(Bs + (c - 8) * 512), 16, 0, 0);
            }
        }
        __syncthreads();   // compiler emits vmcnt(0) drain before s_barrier

        bf16x8 af[4], bf[4];
#pragma unroll
        for (int t = 0; t < 4; ++t) {
            af[t] = *(const bf16x8*)(&As[(wm * 64 + t * 16 + l16) * BK + quad * 8]);
            bf[t] = *(const bf16x8*)(&Bs[(wn * 64 + t * 16 + l16) * BK + quad * 8]);
        }
#pragma unroll
        for (int am = 0; am < 4; ++am)
#pragma unroll
            for (int bn = 0; bn < 4; ++bn)
                acc[am][bn] = __builtin_amdgcn_mfma_f32_16x16x32_bf16(
                    af[am], bf[bn], acc[am][bn], 0, 0, 0);
        __syncthreads();
    }

    // Epilogue: C/D layout col=l16, row=quad*4+r (m89/m91-verified).
#pragma unroll
    for (int am = 0; am < 4; ++am) {
        int row_base = m0 + wm * 64 + am * 16 + quad * 4;
#pragma unroll
        for (int bn = 0; bn < 4; ++bn) {
            int col = n0 + wn * 64 + bn * 16 + l16;
            float bv = bias[col];
#pragma unroll
            for (int rr = 0; rr < 4; ++rr) {
                int rowi = row_base + rr;
                if (rowi < NN) out[(size_t)rowi * DD + col] = acc[am][bn][rr] + bv;
            }
        }
    }
}

extern "C" void kernel_launch(void* const* d_in, const int* in_sizes, int n_in,
                              void* d_out, int out_size, void* d_ws, size_t ws_size,
                              hipStream_t stream) {
    const float* x    = (const float*)d_in[0];
    const float* W    = (const float*)d_in[1];
    const float* bias = (const float*)d_in[2];
    const int*   src  = (const int*)d_in[3];
    const int*   dst  = (const int*)d_in[4];
    float* out = (float*)d_out;
    (void)d_ws; (void)ws_size;

    prep_all<<<FB_END, 256, 0, stream>>>(x, W, src, dst);        // fill || conv || Wt
    aggregate<<<(NN * 64 + 255) / 256, 256, 0, stream>>>();      // one wave/node
    gemm_kernel<<<NWG, 512, 0, stream>>>(out, bias);             // timed once...
    gemm_kernel<<<NWG, 512, 0, stream>>>(out, bias);             // ...probe dup 1
    gemm_kernel<<<NWG, 512, 0, stream>>>(out, bias);             // ...probe dup 2
}

// Round 9
// 507.797 us; speedup vs baseline: 1.0077x; 1.0077x over previous
//
#include <hip/hip_runtime.h>
#include <hip/hip_bf16.h>

#define NN 50000
#define NE 800000
#define DD 512
#define STRIDE 96    // bucket-CSR slot count; P(deg >= 96) ~ 1e-30 for Poisson(16)
#define NBLK 391     // ceil(NN / 128): fused blocks, 128 rows each
#define LDA_A 520    // 512 + 8 pad shorts: row = 1040 B (16B-aligned, breaks bank stride)

typedef __attribute__((ext_vector_type(8))) short bf16x8;
typedef __attribute__((ext_vector_type(4))) float f32x4;
typedef __attribute__((ext_vector_type(8))) unsigned short u16x8;

// R9: fuse aggregate+GEMM. R8 attribution: gemm ~54 us warm, agg 131.5, and
// >= 86 us of inter-kernel gap/overhead. The gemm tile [m0,m0+128) depends only
// on aggregation of those rows -> fuse per-block with __syncthreads, killing the
// g_agg 51MB-write + 102MB-read round trip, one launch gap, and overlapping
// gather (fabric) with MFMA (matrix pipe) across co-resident blocks.
__device__ __align__(16) unsigned short g_Wt[DD * DD];            // W^T bf16
__device__ __align__(16) unsigned short g_xb[(size_t)NN * DD];    // x in bf16 (51 MB)
__device__ unsigned g_cnt[NN];                                    // static zero-init
__device__ int g_eidx[(size_t)NN * STRIDE];                       // bucket CSR

// round-to-nearest-even fp32 -> bf16 (finite normal inputs)
static __device__ __forceinline__ unsigned short f2bf(float f) {
    unsigned u = __float_as_uint(f);
    u += 0x7fff + ((u >> 16) & 1);
    return (unsigned short)(u >> 16);
}
static __device__ __forceinline__ float bf2f(unsigned short u) {
    return __uint_as_float((unsigned)u << 16);
}

// Fused prep: fill (edge scatter) || x->bf16 conv || W^T. (pad-zero branch gone:
// no g_agg anymore.) All stores NORMAL (R1: NT scatter stores regress).
#define FB_FILL 3125                 // 800000 / 256 exactly
#define FB_CONV (FB_FILL + 12500)    // 50000*512/8/256
#define FB_WT   (FB_CONV + 1024)     // 512*512/256

__global__ void prep_all(const float* __restrict__ x, const float* __restrict__ W,
                         const int* __restrict__ src, const int* __restrict__ dst) {
    int b = blockIdx.x;
    int tid = threadIdx.x;
    if (b < FB_FILL) {
        int i = b * 256 + tid;                     // NE = 3125*256 exactly
        int d = dst[i];
        unsigned pos = atomicAdd(&g_cnt[d], 1u);
        if (pos < STRIDE) g_eidx[(size_t)d * STRIDE + pos] = src[i];
    } else if (b < FB_CONV) {
        size_t base = ((size_t)(b - FB_FILL) * 256 + tid) * 8;
        // x is read exactly once: nontemporal load, don't install 102 MB in L2
        f32x4 v0 = __builtin_nontemporal_load((const f32x4*)(x + base));
        f32x4 v1 = __builtin_nontemporal_load((const f32x4*)(x + base) + 1);
        u16x8 o;
        o[0] = f2bf(v0[0]); o[1] = f2bf(v0[1]); o[2] = f2bf(v0[2]); o[3] = f2bf(v0[3]);
        o[4] = f2bf(v1[0]); o[5] = f2bf(v1[1]); o[6] = f2bf(v1[2]); o[7] = f2bf(v1[3]);
        *(u16x8*)(g_xb + base) = o;                // normal store
    } else {
        int idx = (b - FB_CONV) * 256 + tid;       // coalesced read of W
        int k = idx >> 9, n = idx & 511;
        g_Wt[n * DD + k] = f2bf(W[idx]);           // g_Wt[n][k] = W[k][n]
    }
}

// Fused aggregate+GEMM: block b owns rows [b*128, b*128+128), in 4 quarters of 32.
// Per quarter: 8 waves aggregate 4 nodes each -> As (bf16, LDS), barrier via the
// k-loop's staging sync, then C[32x512] = As @ W^T with Bs[512][32] staged per
// k-step (R6's proven global_load_lds pattern). LDS 64.5 KB -> 2 blocks/CU,
// 391 blocks all co-resident (no tail rounds); gather and MFMA overlap across
// CU-mate blocks. Epilogue adds bias, writes fp32 out directly.
__global__ __launch_bounds__(512) void agg_gemm(float* __restrict__ out,
                                                const float* __restrict__ bias) {
    __shared__ __align__(16) unsigned short As[32 * LDA_A];   // 33,280 B
    __shared__ __align__(16) unsigned short Bs[512 * 32];     // 32,768 B
    const int m_base = blockIdx.x * 128;
    const int tid = threadIdx.x;
    const int wave = tid >> 6, lane = tid & 63;
    const int quad = lane >> 4, l16 = lane & 15;

    for (int qtr = 0; qtr < 4; ++qtr) {
        const int r0 = m_base + qtr * 32;
        // ---- aggregate: wave handles LDS rows wave*4 .. wave*4+4 ----
        for (int nn = 0; nn < 4; ++nn) {
            const int lrow = wave * 4 + nn;
            const int v = r0 + lrow;
            float a[8] = {0.f, 0.f, 0.f, 0.f, 0.f, 0.f, 0.f, 0.f};
            if (v < NN) {
                int deg = (int)g_cnt[v];
                if (deg > STRIDE) deg = STRIDE;
                const int* seg = g_eidx + (size_t)v * STRIDE;
                int i = 0;
                for (; i + 3 < deg; i += 4) {  // 4 KB in flight per wave
                    int s0 = seg[i], s1 = seg[i + 1], s2 = seg[i + 2], s3 = seg[i + 3];
                    int4 q0 = *((const int4*)(g_xb + ((size_t)s0 << 9)) + lane);
                    int4 q1 = *((const int4*)(g_xb + ((size_t)s1 << 9)) + lane);
                    int4 q2 = *((const int4*)(g_xb + ((size_t)s2 << 9)) + lane);
                    int4 q3 = *((const int4*)(g_xb + ((size_t)s3 << 9)) + lane);
                    const unsigned short* u0 = (const unsigned short*)&q0;
                    const unsigned short* u1 = (const unsigned short*)&q1;
                    const unsigned short* u2 = (const unsigned short*)&q2;
                    const unsigned short* u3 = (const unsigned short*)&q3;
#pragma unroll
                    for (int j = 0; j < 8; ++j)
                        a[j] += (bf2f(u0[j]) + bf2f(u1[j])) + (bf2f(u2[j]) + bf2f(u3[j]));
                }
                for (; i + 1 < deg; i += 2) {
                    int s0 = seg[i], s1 = seg[i + 1];
                    int4 q0 = *((const int4*)(g_xb + ((size_t)s0 << 9)) + lane);
                    int4 q1 = *((const int4*)(g_xb + ((size_t)s1 << 9)) + lane);
                    const unsigned short* u0 = (const unsigned short*)&q0;
                    const unsigned short* u1 = (const unsigned short*)&q1;
#pragma unroll
                    for (int j = 0; j < 8; ++j) a[j] += bf2f(u0[j]) + bf2f(u1[j]);
                }
                if (i < deg) {
                    int s0 = seg[i];
                    int4 q0 = *((const int4*)(g_xb + ((size_t)s0 << 9)) + lane);
                    const unsigned short* u0 = (const unsigned short*)&q0;
#pragma unroll
                    for (int j = 0; j < 8; ++j) a[j] += bf2f(u0[j]);
                }
            }
            u16x8 o;
#pragma unroll
            for (int j = 0; j < 8; ++j) o[j] = f2bf(a[j]);
            *(u16x8*)(&As[lrow * LDA_A + lane * 8]) = o;   // 16B, consecutive lanes
        }
        // ---- GEMM quarter: C[32 x 512] = As @ W^T ----
        f32x4 acc[2][4];
#pragma unroll
        for (int m = 0; m < 2; ++m)
#pragma unroll
            for (int g = 0; g < 4; ++g) acc[m][g] = (f32x4){0.f, 0.f, 0.f, 0.f};

        for (int k0 = 0; k0 < DD; k0 += 32) {
            // stage Bs[512][32]: 2048 x 16B chunks, 4 per thread; wave-uniform
            // LDS base + lane*16 (chunk = i*512 + wave*64 + lane -> linear dst).
#pragma unroll
            for (int i = 0; i < 4; ++i) {
                int c = i * 512 + tid;
                int n = c >> 2;
                int koff = (c & 3) * 8;
                __builtin_amdgcn_global_load_lds(
                    (const __attribute__((address_space(1))) void*)
                        (g_Wt + (size_t)n * DD + k0 + koff),
                    (__attribute__((address_space(3))) void*)(Bs + (size_t)c * 8), 16, 0, 0);
            }
            __syncthreads();   // drains vmcnt (Bs) AND lgkmcnt (As ds_writes)

            bf16x8 af[2], bf[4];
            af[0] = *(const bf16x8*)(&As[l16 * LDA_A + k0 + quad * 8]);
            af[1] = *(const bf16x8*)(&As[(16 + l16) * LDA_A + k0 + quad * 8]);
#pragma unroll
            for (int g = 0; g < 4; ++g)
                bf[g] = *(const bf16x8*)(&Bs[(wave * 64 + g * 16 + l16) * 32 + quad * 8]);
#pragma unroll
            for (int m = 0; m < 2; ++m)
#pragma unroll
                for (int g = 0; g < 4; ++g)
                    acc[m][g] = __builtin_amdgcn_mfma_f32_16x16x32_bf16(
                        af[m], bf[g], acc[m][g], 0, 0, 0);
            __syncthreads();   // all reads done before Bs restage / As rewrite
        }
        // ---- epilogue: C/D col=l16, row=quad*4+reg (m89/m91-verified) ----
        // Register-only; next quarter's As writes are safe (all As reads precede
        // the k-loop's final barrier, which every wave has passed).
#pragma unroll
        for (int m = 0; m < 2; ++m) {
            int row_base = r0 + m * 16 + quad * 4;
#pragma unroll
            for (int g = 0; g < 4; ++g) {
                int col = wave * 64 + g * 16 + l16;
                float bv = bias[col];
#pragma unroll
                for (int rr = 0; rr < 4; ++rr) {
                    int row = row_base + rr;
                    if (row < NN) out[(size_t)row * DD + col] = acc[m][g][rr] + bv;
                }
            }
        }
    }
    // zero this block's g_cnt range for the next graph replay (all reads of
    // these counters were by this block's waves, before the last k-loop barrier)
    if (tid < 128) {
        int v = m_base + tid;
        if (v < NN) g_cnt[v] = 0;
    }
}

extern "C" void kernel_launch(void* const* d_in, const int* in_sizes, int n_in,
                              void* d_out, int out_size, void* d_ws, size_t ws_size,
                              hipStream_t stream) {
    const float* x    = (const float*)d_in[0];
    const float* W    = (const float*)d_in[1];
    const float* bias = (const float*)d_in[2];
    const int*   src  = (const int*)d_in[3];
    const int*   dst  = (const int*)d_in[4];
    float* out = (float*)d_out;
    (void)d_ws; (void)ws_size;

    prep_all<<<FB_WT, 256, 0, stream>>>(x, W, src, dst);   // fill || conv || Wt
    agg_gemm<<<NBLK, 512, 0, stream>>>(out, bias);         // fused gather+GEMM
}